// Round 12
// baseline (359.306 us; speedup 1.0000x reference)
//
#include <hip/hip_runtime.h>
#include <stdint.h>

// ---------------------------------------------------------------------------
// FeatureMapTransformer: dual cross-attention (rd / dr paths), B=2, C=512,
// H=W=64 -> N=M=4096.
//   Qt[n][c], Kt[m][c], V[c][m] produced DIRECTLY from f32 x (k_conv
//     fuses the f32->bf16 transpose -- k_tcvt ELIMINATED, r12)
//   Et[n][m] = bf16(exp(sum_c Kt[m][c] Qt[n][c]))             (k_qk)
//   partial S[m] = sum_n exp(T) fused into k_qk               (k_qk)
//   c[m] = 1/S; V'[c][m] = V[c][m]*c[m]  (merged)             (k_scale)
//   O[c][n]  = sum_m V'[c][m] E[n][m]  (split-K bf16 GEMM)    (k_pv)
//   out = relu(gamma*(P0+P1) + resid)                         (k_red)
// Round-21 (r12): k_tcvt was ~65 us of pure BW (402 MB: 268 f32 read +
// 134 bf16 write) existing only to make x c-contiguous for MFMA. Fused
// into k_conv: X tile (32c x 256n) reg-staged from f32 x[c][n] -- thread
// t: n = t&255, c0 = (t>>8)*16; 16 lane-coalesced global f32 loads (64
// lanes x 4B consecutive n), f2bf x16, pack -> 2 ds_write_b128 into the
// SAME swizzled [n][c] layout the frag readers use (bit-identical math).
// Staging discipline: ALL staging one tile ahead into NXT (X-writes +
// W-DMA) -- nxt's regions were last read before the previous tile's
// closing barriers for BOTH trans and V orientations (the old same-phase
// cur-staging would race for V convs where W = A region). Single
// vmcnt(0) at p0 entry; in-flight ops (16 X-loads + 2 W-DMA, issued one
// full tile earlier ~1200cyc) have landed. LDS stays 64 KB, 2 blk/CU.
// k_qk (32x32 core, r11) / k_pv (split-K, r9) / k_scale / k_red kept.
// ---------------------------------------------------------------------------

typedef __attribute__((ext_vector_type(8))) __bf16 bf16x8;
typedef __attribute__((ext_vector_type(4))) float f32x4;
typedef __attribute__((ext_vector_type(16))) float f32x16;

__device__ __forceinline__ unsigned short f2bf(float f) {
  union { float f; unsigned u; } v; v.f = f;
  unsigned r = v.u + 0x7FFFu + ((v.u >> 16) & 1u);
  return (unsigned short)(r >> 16);
}
__device__ __forceinline__ float bf2f(unsigned short b) {
  union { unsigned u; float f; } v; v.u = ((unsigned)b) << 16;
  return v.f;
}

__device__ __forceinline__ void async_copy16(const unsigned short* g,
                                             unsigned short* l) {
  __builtin_amdgcn_global_load_lds(
      (const __attribute__((address_space(1))) unsigned int*)g,
      (__attribute__((address_space(3))) unsigned int*)l, 16, 0, 0);
}

// Counted VMEM wait (literal immediates only). Memory clobber pins all
// memory ops (ds_read / global_load_lds / global_load) on the right side.
template <int N>
__device__ __forceinline__ void waitcnt_vm() {
  if constexpr (N == 0) asm volatile("s_waitcnt vmcnt(0)" ::: "memory");
  else if constexpr (N == 2) asm volatile("s_waitcnt vmcnt(2)" ::: "memory");
  else if constexpr (N == 4) asm volatile("s_waitcnt vmcnt(4)" ::: "memory");
  else if constexpr (N == 6) asm volatile("s_waitcnt vmcnt(6)" ::: "memory");
  else asm volatile("s_waitcnt vmcnt(8)" ::: "memory");
}

// ---------------- 256^2 GEMM core, 32x32x16 (k_qk) -----------------------
// r11 core, unchanged (verified).
__device__ __forceinline__ void gemm256q(
    const unsigned short* __restrict__ Ag, const unsigned short* __restrict__ Bg,
    int rowbase, int colbase, f32x16 (&acc)[4][2], unsigned short* sh) {
  const int tid = threadIdx.x;
  const int w = tid >> 6, lane = tid & 63;
  const int l32 = lane & 31, lh = lane >> 5;
  const int wm = (w >> 2) << 7;   // A-row offset 0/128
  const int wn = (w & 3) << 6;    // B-row offset 0/64/128/192
  const int srow = tid >> 2;
  const int scg  = (tid & 3) ^ ((srow >> 1) & 3);

  auto stageA = [&](int kg, unsigned short* buf) {
#pragma unroll
    for (int r = 0; r < 2; ++r) {
      int row = srow + (r << 7);
      async_copy16(Ag + (size_t)(rowbase + row) * 512 + kg + (scg << 3),
                   buf + (r << 12) + (w << 9));
    }
  };
  auto stageB = [&](int kg, unsigned short* buf) {
#pragma unroll
    for (int r = 0; r < 2; ++r) {
      int row = srow + (r << 7);
      async_copy16(Bg + (size_t)(colbase + row) * 512 + kg + (scg << 3),
                   buf + 8192 + (r << 12) + (w << 9));
    }
  };
  bf16x8 af[4], bfv[2][2];
  auto rdA = [&](const unsigned short* buf, int kh) {
#pragma unroll
    for (int i = 0; i < 4; ++i) {
      int r = wm + (i << 5) + l32;
      int ck = (kh << 1) + lh;
      af[i] = *(const bf16x8*)(buf + (r << 5) + ((ck ^ ((r >> 1) & 3)) << 3));
    }
  };
  auto rdB4 = [&](const unsigned short* buf) {
#pragma unroll
    for (int j = 0; j < 2; ++j)
#pragma unroll
      for (int kh = 0; kh < 2; ++kh) {
        int r = wn + (j << 5) + l32;
        int ck = (kh << 1) + lh;
        bfv[j][kh] = *(const bf16x8*)(buf + 8192 + (r << 5) + ((ck ^ ((r >> 1) & 3)) << 3));
      }
  };
  auto mfmaK = [&](int kh) {
#pragma unroll
    for (int i = 0; i < 4; ++i)
#pragma unroll
      for (int j = 0; j < 2; ++j)
        acc[i][j] = __builtin_amdgcn_mfma_f32_32x32x16_bf16(af[i], bfv[j][kh], acc[i][j], 0, 0, 0);
  };

  unsigned short* b0 = sh;
  unsigned short* b1 = sh + 16384;

  stageA(0, b0); stageB(0, b0); stageB(32, b1);
  waitcnt_vm<2>();
  __builtin_amdgcn_s_barrier();

  for (int t = 0; t < 16; ++t) {
    unsigned short* cur = (t & 1) ? b1 : b0;
    unsigned short* nxt = (t & 1) ? b0 : b1;
    rdB4(cur);
    rdA(cur, 0);
    if (t + 1 < 16) stageA((t + 1) << 5, nxt);
    __builtin_amdgcn_s_barrier();
    __builtin_amdgcn_s_setprio(1); mfmaK(0); __builtin_amdgcn_s_setprio(0);
    __builtin_amdgcn_s_barrier();
    rdA(cur, 1);
    if (t + 2 < 16) stageB((t + 2) << 5, cur);
    __builtin_amdgcn_s_barrier();
    __builtin_amdgcn_s_setprio(1); mfmaK(1); __builtin_amdgcn_s_setprio(0);
    if (t < 14) waitcnt_vm<2>(); else waitcnt_vm<0>();
    __builtin_amdgcn_s_barrier();
  }
}

// ---------------- weight fp32 -> bf16 (vectorized) -----------------------
struct WArgs { const float* src[6]; unsigned short* dst[6]; };
__global__ __launch_bounds__(256) void k_cvtw(WArgs a) {
  int z = blockIdx.y;
  int i = (blockIdx.x * 256 + threadIdx.x) << 3;
  const float* s = a.src[z] + i;
  float4 v0 = *(const float4*)s;
  float4 v1 = *(const float4*)(s + 4);
  unsigned short pk[8] = {f2bf(v0.x), f2bf(v0.y), f2bf(v0.z), f2bf(v0.w),
                          f2bf(v1.x), f2bf(v1.y), f2bf(v1.z), f2bf(v1.w)};
  *(int4*)(a.dst[z] + i) = *(int4*)pk;
}

// ---------------- conv1x1 GEMMs: Y = W X^T + bias, fused transpose ------
// X (f32 x[c][n]) reg-staged with on-the-fly f32->bf16 + transpose into
// the swizzled [n][c] LDS layout; W DMA-staged. trans=1 (Q,K): A=X rows
// n, B=W rows o, out[n][o]. trans=0 (V): A=W rows o, B=X rows n,
// out[o][n]. All staging one tile ahead into NXT; vmcnt(0) at p0 entry.
// Grid (16,2,12) x 512 thr, LDS 64 KB.
struct ConvArgs {
  const unsigned short* W[12];
  const float* X[12];          // f32 x[c][n], batch-adjusted
  const float* bias[12];
  unsigned short* out[12];
  int trans[12];
};
__global__ __launch_bounds__(512) void k_conv(ConvArgs a) {
  __shared__ unsigned short sh[32768];  // 2 buf x (A 8192 + B 8192 shorts)
  int z = blockIdx.z;
  int trans = a.trans[z];
  int rowbase = (trans ? blockIdx.x : blockIdx.y) << 8;
  int colbase = (trans ? blockIdx.y : blockIdx.x) << 8;
  const int nXbase = trans ? rowbase : colbase;  // X rows = n
  const int obase  = trans ? colbase : rowbase;  // W rows = o
  const int xRegion = trans ? 0 : 8192;          // X -> A : B region
  const int wRegion = trans ? 8192 : 0;          // W -> B : A region
  const unsigned short* Wg = a.W[z];
  const float* Xg = a.X[z];

  const int tid = threadIdx.x;
  const int w = tid >> 6, lane = tid & 63;
  const int quad = lane >> 4, l16 = lane & 15;
  const int wm = (w >> 2) << 7, wn = (w & 3) << 6;
  const int srow = tid >> 2;                      // 0..127 (W staging)
  const int scg  = (tid & 3) ^ ((srow >> 1) & 3);
  // X staging: thread -> one n row, 16 c (2 chunks)
  const int xn = tid & 255;
  const int xc0 = (tid >> 8) << 4;      // 0 or 16
  const int xck = xc0 >> 3;             // chunk 0 or 2

  f32x4 acc[8][4];
#pragma unroll
  for (int i = 0; i < 8; ++i)
#pragma unroll
    for (int j = 0; j < 4; ++j) acc[i][j] = (f32x4){0.f, 0.f, 0.f, 0.f};

  float xr[16];
  auto ldX = [&](int kg) {
#pragma unroll
    for (int i = 0; i < 16; ++i)
      xr[i] = Xg[(size_t)(kg + xc0 + i) * 4096 + nXbase + xn];
  };
  auto wrX = [&](unsigned short* buf) {
    unsigned short pk[16];
#pragma unroll
    for (int i = 0; i < 16; ++i) pk[i] = f2bf(xr[i]);
    int sw = (xn >> 1) & 3;
    unsigned short* row = buf + xRegion + (xn << 5);
    *(int4*)(row + ((xck ^ sw) << 3))       = *(int4*)pk;
    *(int4*)(row + (((xck + 1) ^ sw) << 3)) = *(int4*)(pk + 8);
  };
  auto dmaW = [&](int kg, unsigned short* buf) {
#pragma unroll
    for (int r = 0; r < 2; ++r) {
      int row = srow + (r << 7);
      async_copy16(Wg + (size_t)(obase + row) * 512 + kg + (scg << 3),
                   buf + wRegion + (r << 12) + (w << 9));
    }
  };

  bf16x8 af[4], bfv[4];
  auto rdA = [&](const unsigned short* buf, int half) {
#pragma unroll
    for (int i = 0; i < 4; ++i) {
      int r = wm + (half << 6) + (i << 4) + l16;
      af[i] = *(const bf16x8*)(buf + (r << 5) + ((quad ^ ((r >> 1) & 3)) << 3));
    }
  };
  auto rdB = [&](const unsigned short* buf) {
#pragma unroll
    for (int j = 0; j < 4; ++j) {
      int r = wn + (j << 4) + l16;
      bfv[j] = *(const bf16x8*)(buf + 8192 + (r << 5) + ((quad ^ ((r >> 1) & 3)) << 3));
    }
  };
  auto mfmaQ = [&](int ib) {
#pragma unroll
    for (int i = 0; i < 4; ++i)
#pragma unroll
      for (int j = 0; j < 4; ++j)
        acc[ib + i][j] = __builtin_amdgcn_mfma_f32_16x16x32_bf16(af[i], bfv[j], acc[ib + i][j], 0, 0, 0);
  };

  unsigned short* b0 = sh;
  unsigned short* b1 = sh + 16384;

  // prologue: tile0 fully staged; tile1 ops in flight
  ldX(0);
  waitcnt_vm<0>();
  wrX(b0);
  dmaW(0, b0);                 // +2
  ldX(32);                     // +16
  dmaW(32, b1);                // +2
  waitcnt_vm<4>();             // W(0) landed; X(1)+W(1)... W(0) oldest of 20
  // (vmcnt(4) leaves the newest 4; X(1) loads are among the drained 16 --
  //  conservative but correct; X(1) regs then simply ready early.)
  asm volatile("s_waitcnt lgkmcnt(0)" ::: "memory");
  __builtin_amdgcn_s_barrier();

  for (int t = 0; t < 16; ++t) {
    unsigned short* cur = (t & 1) ? b1 : b0;
    unsigned short* nxt = (t & 1) ? b0 : b1;
    // p0: publish tile t+1 into nxt; issue tile t+2 X loads; compute lo
    waitcnt_vm<0>();                       // X(t+1) regs + W(t+1) landed
    if (t + 1 < 16) {
      wrX(nxt);
      dmaW((t + 1) << 5, nxt);
    }
    if (t + 2 < 16) ldX((t + 2) << 5);
    rdB(cur);
    rdA(cur, 0);
    asm volatile("s_waitcnt lgkmcnt(0)" ::: "memory");  // publish wrX
    __builtin_amdgcn_s_barrier();
    __builtin_amdgcn_s_setprio(1); mfmaQ(0); __builtin_amdgcn_s_setprio(0);
    __builtin_amdgcn_s_barrier();
    // p1: compute hi
    rdA(cur, 1);
    __builtin_amdgcn_s_barrier();
    __builtin_amdgcn_s_setprio(1); mfmaQ(4); __builtin_amdgcn_s_setprio(0);
    __builtin_amdgcn_s_barrier();
  }

  const float* bias = a.bias[z];
  unsigned short* out = a.out[z];
  if (trans) {
    float bo[4];
#pragma unroll
    for (int j = 0; j < 4; ++j) bo[j] = bias[colbase + wn + (j << 4) + l16];
#pragma unroll
    for (int i = 0; i < 8; ++i) {
      int n0 = rowbase + wm + ((i >> 2) << 6) + ((i & 3) << 4) + (quad << 2);
#pragma unroll
      for (int j = 0; j < 4; ++j) {
        int o = colbase + wn + (j << 4) + l16;
        out[(size_t)(n0 + 0) * 512 + o] = f2bf(acc[i][j].x + bo[j]);
        out[(size_t)(n0 + 1) * 512 + o] = f2bf(acc[i][j].y + bo[j]);
        out[(size_t)(n0 + 2) * 512 + o] = f2bf(acc[i][j].z + bo[j]);
        out[(size_t)(n0 + 3) * 512 + o] = f2bf(acc[i][j].w + bo[j]);
      }
    }
  } else {
#pragma unroll
    for (int i = 0; i < 8; ++i) {
      int o0 = rowbase + wm + ((i >> 2) << 6) + ((i & 3) << 4) + (quad << 2);
      float b0v = bias[o0], b1v = bias[o0 + 1], b2v = bias[o0 + 2], b3v = bias[o0 + 3];
#pragma unroll
      for (int j = 0; j < 4; ++j) {
        int n = colbase + wn + (j << 4) + l16;
        out[(size_t)(o0 + 0) * 4096 + n] = f2bf(acc[i][j].x + b0v);
        out[(size_t)(o0 + 1) * 4096 + n] = f2bf(acc[i][j].y + b1v);
        out[(size_t)(o0 + 2) * 4096 + n] = f2bf(acc[i][j].z + b2v);
        out[(size_t)(o0 + 3) * 4096 + n] = f2bf(acc[i][j].w + b3v);
      }
    }
  }
}

// ---------------- Et[n][m] = exp(Qt Kt^T), fused partial sum S[m] --------
// OPERAND-SWAPPED: A=Qt (rows=n), B=Kt (cols=m). 256^2 / 32x32x16 core.
struct QKArgs {
  const unsigned short* Q[4]; const unsigned short* K[4]; unsigned short* T[4];
  float* pz;  // [4 z][16 nblk][4096 m] partial sums
};
__global__ __launch_bounds__(512) void k_qk(QKArgs a) {
  __shared__ unsigned short sh[32768];  // 64 KB
  int z = blockIdx.z;
  int nbase = blockIdx.y << 8;
  int mbase = blockIdx.x << 8;
  f32x16 acc[4][2];
#pragma unroll
  for (int i = 0; i < 4; ++i)
#pragma unroll
    for (int j = 0; j < 2; ++j) acc[i][j] = (f32x16)(0.f);
  gemm256q(a.Q[z], a.K[z], nbase, mbase, acc, sh);

  const int tid = threadIdx.x, w = tid >> 6, lane = tid & 63;
  const int l32 = lane & 31, lh = lane >> 5;
  const int wm = (w >> 2) << 7, wn = (w & 3) << 6;
  unsigned short* T = a.T[z];
  float sjv2[2] = {0.f, 0.f};
#pragma unroll
  for (int i = 0; i < 4; ++i) {
    int nb0 = nbase + wm + (i << 5) + (lh << 2);
#pragma unroll
    for (int j = 0; j < 2; ++j) {
      int m = mbase + wn + (j << 5) + l32;
#pragma unroll
      for (int rq = 0; rq < 4; ++rq) {
#pragma unroll
        for (int rr = 0; rr < 4; ++rr) {
          float e = __expf(acc[i][j][(rq << 2) + rr]);
          T[(size_t)(nb0 + (rq << 3) + rr) * 4096 + m] = f2bf(e);
          sjv2[j] += e;
        }
      }
    }
  }
  __syncthreads();
  float* red = (float*)sh;  // [8 waves][64 m-local]
#pragma unroll
  for (int j = 0; j < 2; ++j) {
    float s = sjv2[j];
    s += __shfl_xor(s, 32, 64);
    if (lh == 0) red[(w << 6) + (j << 5) + l32] = s;
  }
  __syncthreads();
  if (tid < 256) {
    float S = red[tid] + red[tid + 256];
    a.pz[((z << 4) + blockIdx.y) * 4096 + mbase + tid] = S;
  }
}

// ---------------- k_scale: c[m]=1/sum(pz); V' = V * c[m] (merged) --------
struct SCArgs { unsigned short* V[4]; const float* pz; };
__global__ __launch_bounds__(256) void k_scale(SCArgs a) {
  __shared__ float cs[256];
  int mbase = blockIdx.x << 8;
  int z = blockIdx.y;
  int rb = blockIdx.z << 6;
  int tid = threadIdx.x;
  float S = 0.f;
#pragma unroll
  for (int k = 0; k < 16; ++k) S += a.pz[((z << 4) + k) * 4096 + mbase + tid];
  cs[tid] = 1.f / S;
  __syncthreads();
  int mloc = (tid & 31) << 3;
  unsigned short* base = a.V[z] + mbase + mloc;
#pragma unroll
  for (int p = 0; p < 8; ++p) {
    int row = rb + (p << 3) + (tid >> 5);
    unsigned short* ptr = base + (size_t)row * 4096;
    int4 raw = *(const int4*)ptr;
    unsigned short* u = (unsigned short*)&raw;
#pragma unroll
    for (int q = 0; q < 8; ++q) u[q] = f2bf(bf2f(u[q]) * cs[mloc + q]);
    *(int4*)ptr = raw;
  }
}

// ---------------- k_pv: P[kh] = V'[:, khalf] E[:, khalf]^T (split-K) -----
// (unchanged from r9 -- validated)
struct PVArgs {
  const unsigned short* V[4];
  const unsigned short* P[4];  // Et[n][m]
  unsigned short* PP[2];       // partials per k-half
};
__global__ __launch_bounds__(512) void k_pv(PVArgs a) {
  __shared__ unsigned short sh[65536];  // 128 KB
  int x = blockIdx.x;            // x = kh + 2z + 8t -> XCD = x&7 = kh+2z
  int kh = x & 1;
  int z  = (x >> 1) & 3;
  int tt = x >> 3;               // 0..31
  int cb = tt & 1;
  int nb = tt >> 1;              // 0..15
  int cbase = cb << 8;
  int nbase = nb << 8;
  int khb = kh << 11;            // k-half base: 0 / 2048
  const unsigned short* Ag = a.V[z];   // V'[c][m], stride 4096
  const unsigned short* Bg = a.P[z];   // E[n][m],  stride 4096

  const int tid = threadIdx.x;
  const int w = tid >> 6, lane = tid & 63;
  const int quad = lane >> 4, l16 = lane & 15;
  const int wm = (w >> 2) << 7;   // c offset 0/128
  const int wn = (w & 3) << 6;    // n offset 0/64/128/192

  f32x4 acc[8][4];
#pragma unroll
  for (int i = 0; i < 8; ++i)
#pragma unroll
    for (int j = 0; j < 4; ++j) acc[i][j] = (f32x4){0.f, 0.f, 0.f, 0.f};

  auto stageA = [&](int kg, int ksub, unsigned short* buf) {
#pragma unroll
    for (int r = 0; r < 2; ++r) {
      int row = (tid >> 2) + (r << 7);
      int cg = (tid & 3) ^ ((row >> 1) & 3);
      async_copy16(Ag + (size_t)(cbase + row) * 4096 + kg + (ksub << 5) + (cg << 3),
                   buf + (ksub << 13) + (r << 12) + (w << 9));
    }
  };
  auto stageB = [&](int kg, int ksub, unsigned short* buf) {
#pragma unroll
    for (int r = 0; r < 2; ++r) {
      int row = (tid >> 2) + (r << 7);
      int cg = (tid & 3) ^ ((row >> 1) & 3);
      async_copy16(Bg + (size_t)(nbase + row) * 4096 + kg + (ksub << 5) + (cg << 3),
                   buf + 16384 + (ksub << 13) + (r << 12) + (w << 9));
    }
  };

  bf16x8 afv[4], bfv[4];
  auto rdA = [&](const unsigned short* buf, int ksub, int half) {
    const unsigned short* As = buf + (ksub << 13);
#pragma unroll
    for (int i = 0; i < 4; ++i) {
      int r = wm + (half << 6) + (i << 4) + l16;
      afv[i] = *(const bf16x8*)(As + (r << 5) + ((quad ^ ((r >> 1) & 3)) << 3));
    }
  };
  auto rdB = [&](const unsigned short* buf, int ksub) {
    const unsigned short* Bs = buf + 16384 + (ksub << 13);
#pragma unroll
    for (int j = 0; j < 4; ++j) {
      int r = wn + (j << 4) + l16;
      bfv[j] = *(const bf16x8*)(Bs + (r << 5) + ((quad ^ ((r >> 1) & 3)) << 3));
    }
  };
  auto mfmaQ = [&](int ib) {
#pragma unroll
    for (int i = 0; i < 4; ++i)
#pragma unroll
      for (int j = 0; j < 4; ++j)
        acc[ib + i][j] = __builtin_amdgcn_mfma_f32_16x16x32_bf16(afv[i], bfv[j], acc[ib + i][j], 0, 0, 0);
  };

  unsigned short* b0 = sh;
  unsigned short* b1 = sh + 32768;

  stageA(khb, 0, b0); stageA(khb, 1, b0); stageB(khb, 0, b0); stageB(khb, 1, b0);
  stageB(khb + 64, 0, b1); stageA(khb + 64, 0, b1); stageB(khb + 64, 1, b1);
  waitcnt_vm<6>();
  __builtin_amdgcn_s_barrier();

  for (int t = 0; t < 32; ++t) {
    unsigned short* cur = (t & 1) ? b1 : b0;
    unsigned short* nxt = (t & 1) ? b0 : b1;
    int kgc = khb + ((t + 2) << 6);
    rdB(cur, 0);
    rdA(cur, 0, 0);
    if (t + 1 < 32) stageA(khb + ((t + 1) << 6), 1, nxt);
    __builtin_amdgcn_s_barrier();
    __builtin_amdgcn_s_setprio(1); mfmaQ(0); __builtin_amdgcn_s_setprio(0);
    __builtin_amdgcn_s_barrier();
    rdA(cur, 0, 1);
    if (t + 2 < 32) stageB(kgc, 0, cur);
    __builtin_amdgcn_s_barrier();
    __builtin_amdgcn_s_setprio(1); mfmaQ(4); __builtin_amdgcn_s_setprio(0);
    __builtin_amdgcn_s_barrier();
    rdB(cur, 1);
    rdA(cur, 1, 0);
    if (t + 2 < 32) stageA(kgc, 0, cur);
    __builtin_amdgcn_s_barrier();
    __builtin_amdgcn_s_setprio(1); mfmaQ(0); __builtin_amdgcn_s_setprio(0);
    __builtin_amdgcn_s_barrier();
    rdA(cur, 1, 1);
    if (t + 2 < 32) stageB(kgc, 1, cur);
    __builtin_amdgcn_s_barrier();
    __builtin_amdgcn_s_setprio(1); mfmaQ(4); __builtin_amdgcn_s_setprio(0);
    if (t < 30) waitcnt_vm<6>(); else waitcnt_vm<0>();
    __builtin_amdgcn_s_barrier();
  }

  unsigned short* PP = a.PP[kh] + (size_t)z * 2097152;
#pragma unroll
  for (int i = 0; i < 8; ++i) {
    int c0 = cbase + wm + ((i >> 2) << 6) + ((i & 3) << 4) + (quad << 2);
#pragma unroll
    for (int j = 0; j < 4; ++j) {
      int n = nbase + wn + (j << 4) + l16;
      PP[(size_t)(c0 + 0) * 4096 + n] = f2bf(acc[i][j].x);
      PP[(size_t)(c0 + 1) * 4096 + n] = f2bf(acc[i][j].y);
      PP[(size_t)(c0 + 2) * 4096 + n] = f2bf(acc[i][j].z);
      PP[(size_t)(c0 + 3) * 4096 + n] = f2bf(acc[i][j].w);
    }
  }
}

// ---------------- k_red: out = relu(gamma*(P0+P1) + resid) ---------------
struct RArgs {
  const unsigned short* PP[2];
  const float* resid[4];
  const float* gamma[4];
  float* out[4];
};
__global__ __launch_bounds__(256) void k_red(RArgs a) {
  int z = blockIdx.y;
  size_t i = (((size_t)blockIdx.x << 8) + threadIdx.x) << 3;
  int4 q0 = *(const int4*)(a.PP[0] + (size_t)z * 2097152 + i);
  int4 q1 = *(const int4*)(a.PP[1] + (size_t)z * 2097152 + i);
  const unsigned short* u0 = (const unsigned short*)&q0;
  const unsigned short* u1 = (const unsigned short*)&q1;
  float g = a.gamma[z][0];
  const float* R = a.resid[z] + i;
  float4 r0 = *(const float4*)R;
  float4 r1 = *(const float4*)(R + 4);
  const float* rv = (const float*)&r0;
  const float* rw = (const float*)&r1;
  float res[8];
#pragma unroll
  for (int k = 0; k < 4; ++k)
    res[k] = fmaxf(g * (bf2f(u0[k]) + bf2f(u1[k])) + rv[k], 0.f);
#pragma unroll
  for (int k = 4; k < 8; ++k)
    res[k] = fmaxf(g * (bf2f(u0[k]) + bf2f(u1[k])) + rw[k - 4], 0.f);
  float* O = a.out[z] + i;
  *(float4*)O = *(float4*)res;
  *(float4*)(O + 4) = *(float4*)(res + 4);
}

// ---------------------------------------------------------------------------
extern "C" void kernel_launch(void* const* d_in, const int* in_sizes, int n_in,
                              void* d_out, int out_size, void* d_ws, size_t ws_size,
                              hipStream_t stream) {
  char* ws = (char*)d_ws;
  unsigned short* wb  = (unsigned short*)(ws);              //  6 x 512x512 bf16
  unsigned short* qkv = (unsigned short*)(ws + 36700160);   // 12 x [4096x512]
  unsigned short* tt  = (unsigned short*)(ws + 87031808);   //  4 x [4096x4096]
  float* pz  = (float*)(ws + 3145728);                      // scratch
  // split-K partials reuse dead Q/K conv outputs (each exactly 16777216 B):
  unsigned short* pp0 = qkv;                          // slots 0-3 (Q_rd,K_rd)
  unsigned short* pp1 = qkv + (size_t)6 * 2097152;    // slots 6-9 (Q_dr,K_dr)

  // 1. weights -> bf16
  WArgs wa;
  for (int i = 0; i < 6; ++i) {
    wa.src[i] = (const float*)d_in[4 + 2 * i];
    wa.dst[i] = wb + (size_t)i * 262144;
  }
  k_cvtw<<<dim3(128, 6), 256, 0, stream>>>(wa);

  // 2. six convs x two batches (fused f32 transpose; 384 blocks x 512 thr)
  const int srcArr[6] = {2, 0, 3, 3, 1, 1};
  const int trans[6] = {1, 1, 0, 1, 1, 0};
  ConvArgs ca;
  for (int ci = 0; ci < 6; ++ci)
    for (int b = 0; b < 2; ++b) {
      int zz = ci * 2 + b;
      ca.W[zz] = wb + (size_t)ci * 262144;
      ca.X[zz] = (const float*)d_in[srcArr[ci]] + (size_t)b * 2097152;
      ca.bias[zz] = (const float*)d_in[5 + 2 * ci];
      ca.out[zz] = qkv + (size_t)zz * 2097152;
      ca.trans[zz] = trans[ci];
    }
  k_conv<<<dim3(16, 2, 12), 512, 0, stream>>>(ca);

  // 3. Et[n][m] = exp(Qt Kt^T) + fused partial sums (256^2, 32x32 MFMA)
  QKArgs qa;
  for (int path = 0; path < 2; ++path)
    for (int b = 0; b < 2; ++b) {
      int zz = path * 2 + b;
      qa.Q[zz] = qkv + (size_t)((path * 3 + 0) * 2 + b) * 2097152;  // Qt (rows=n)
      qa.K[zz] = qkv + (size_t)((path * 3 + 1) * 2 + b) * 2097152;  // Kt (cols=m)
      qa.T[zz] = tt + (size_t)zz * 16777216;
    }
  qa.pz = pz;
  k_qk<<<dim3(16, 16, 4), 512, 0, stream>>>(qa);

  // 4. merged: c[m] = 1/sum(pz), V' = V * c[m]
  SCArgs sa;
  for (int path = 0; path < 2; ++path)
    for (int b = 0; b < 2; ++b)
      sa.V[path * 2 + b] = qkv + (size_t)((path * 3 + 2) * 2 + b) * 2097152;
  sa.pz = pz;
  k_scale<<<dim3(16, 4, 8), 256, 0, stream>>>(sa);

  // 5. split-K PV partials (256^2 tile, wave 128x64, 4-phase, full fill)
  PVArgs pa;
  for (int path = 0; path < 2; ++path)
    for (int b = 0; b < 2; ++b) {
      int zz = path * 2 + b;
      pa.V[zz] = qkv + (size_t)((path * 3 + 2) * 2 + b) * 2097152;
      pa.P[zz] = tt + (size_t)zz * 16777216;
    }
  pa.PP[0] = pp0;
  pa.PP[1] = pp1;
  k_pv<<<dim3(256), 512, 0, stream>>>(pa);

  // 6. reduce + fused epilogue
  RArgs ra;
  const float* resid_src[2] = {(const float*)d_in[2], (const float*)d_in[3]};
  const float* gsrc[2] = {(const float*)d_in[16], (const float*)d_in[17]};
  ra.PP[0] = pp0;
  ra.PP[1] = pp1;
  for (int path = 0; path < 2; ++path)
    for (int b = 0; b < 2; ++b) {
      int zz = path * 2 + b;
      ra.resid[zz] = resid_src[path] + (size_t)b * 2097152;
      ra.gamma[zz] = gsrc[path];
      ra.out[zz] = (float*)d_out + (size_t)zz * 2097152;
    }
  k_red<<<dim3(1024, 4), 256, 0, stream>>>(ra);
}